// Round 1
// baseline (205.296 us; speedup 1.0000x reference)
//
#include <hip/hip_runtime.h>
#include <hip/hip_bf16.h>

#define LOG2E 1.4426950408889634f

#if __has_builtin(__builtin_amdgcn_exp2f)
__device__ __forceinline__ float fexp2(float x) { return __builtin_amdgcn_exp2f(x); }
#else
__device__ __forceinline__ float fexp2(float x) { return exp2f(x); }
#endif

#if __has_builtin(__builtin_amdgcn_rcpf)
__device__ __forceinline__ float frcp(float x) { return __builtin_amdgcn_rcpf(x); }
#else
__device__ __forceinline__ float frcp(float x) { return 1.0f / x; }
#endif

// Quad-lane XOR shuffle via DPP quad_perm (full-rate VALU, no LDS pipe).
template<int MASK>
__device__ __forceinline__ float hxor(float v) {
#if __has_builtin(__builtin_amdgcn_update_dpp)
    constexpr int ctrl = (0 ^ MASK) | ((1 ^ MASK) << 2) | ((2 ^ MASK) << 4) | ((3 ^ MASK) << 6);
    return __int_as_float(__builtin_amdgcn_update_dpp(
        0, __float_as_int(v), ctrl, 0xf, 0xf, true));
#else
    return __shfl_xor(v, MASK, 64);
#endif
}

// One lane per hidden unit (H=4), 4 lanes per batch element.
// Gate order (PyTorch): rows 0-3=i, 4-7=f, 8-11=g, 12-15=o.
// All exp2 scale factors pre-folded into weights/biases.
__global__ __launch_bounds__(256) void lstm_h4_kernel(
    const float* __restrict__ x,
    const float* __restrict__ W_ih,   // [16]
    const float* __restrict__ W_hh,   // [16][4]
    const float* __restrict__ b_ih,   // [16]
    const float* __restrict__ b_hh,   // [16]
    const float* __restrict__ fc_w,   // [4]
    const float* __restrict__ fc_b,   // [1]
    float* __restrict__ out,          // [B]
    int B, int T)
{
    const int tid = blockIdx.x * blockDim.x + threadIdx.x;
    const int b = tid >> 2;
    const int j = tid & 3;   // hidden index owned by this lane
    if (b >= B) return;

    const float si = -LOG2E;          // sigmoid gates: E = exp2(-log2e * z) = e^-z
    const float sg = -2.0f * LOG2E;   // tanh gate:    E = exp2(-2 log2e * z) = e^-2z

    const int ri = j, rf = 4 + j, rg = 8 + j, ro = 12 + j;

    // x-path coefficients (I=1): arg_G += A_G * x_t + C_G
    const float Ai = si * W_ih[ri], Ci = si * (b_ih[ri] + b_hh[ri]);
    const float Af = si * W_ih[rf], Cf = si * (b_ih[rf] + b_hh[rf]);
    const float Ag = sg * W_ih[rg], Cg = sg * (b_ih[rg] + b_hh[rg]);
    const float Ao = si * W_ih[ro], Co = si * (b_ih[ro] + b_hh[ro]);

    // Recurrent weights, permuted so index m pairs with h_{j^m}
    const float Wi0 = si * W_hh[ri*4 + (j^0)], Wi1 = si * W_hh[ri*4 + (j^1)];
    const float Wi2 = si * W_hh[ri*4 + (j^2)], Wi3 = si * W_hh[ri*4 + (j^3)];
    const float Wf0 = si * W_hh[rf*4 + (j^0)], Wf1 = si * W_hh[rf*4 + (j^1)];
    const float Wf2 = si * W_hh[rf*4 + (j^2)], Wf3 = si * W_hh[rf*4 + (j^3)];
    const float Wg0 = sg * W_hh[rg*4 + (j^0)], Wg1 = sg * W_hh[rg*4 + (j^1)];
    const float Wg2 = sg * W_hh[rg*4 + (j^2)], Wg3 = sg * W_hh[rg*4 + (j^3)];
    const float Wo0 = si * W_hh[ro*4 + (j^0)], Wo1 = si * W_hh[ro*4 + (j^1)];
    const float Wo2 = si * W_hh[ro*4 + (j^2)], Wo3 = si * W_hh[ro*4 + (j^3)];

    float h = 0.0f, c = 0.0f;

    // c_new = f*c + i*tanh(g) ; with E* = e^{-z} (sigmoid) / e^{-2z} (tanh), p* = 1+E*:
    //   c_new = [c*pi*pg + (1-Eg)*pf] / (pf*pi*pg)           (1 rcp)
    //   h     = (1-Ec) / (po*(1+Ec)),  Ec = e^{-2 c_new}     (1 rcp)
    auto STEP = [&](float xv) {
        const float h1 = hxor<1>(h);
        const float h2 = hxor<2>(h);
        const float h3 = hxor<3>(h);
        float ai = fmaf(Ai, xv, Ci);
        float af = fmaf(Af, xv, Cf);
        float ag = fmaf(Ag, xv, Cg);
        float ao = fmaf(Ao, xv, Co);
        ai = fmaf(Wi0, h, ai); ai = fmaf(Wi1, h1, ai); ai = fmaf(Wi2, h2, ai); ai = fmaf(Wi3, h3, ai);
        af = fmaf(Wf0, h, af); af = fmaf(Wf1, h1, af); af = fmaf(Wf2, h2, af); af = fmaf(Wf3, h3, af);
        ag = fmaf(Wg0, h, ag); ag = fmaf(Wg1, h1, ag); ag = fmaf(Wg2, h2, ag); ag = fmaf(Wg3, h3, ag);
        ao = fmaf(Wo0, h, ao); ao = fmaf(Wo1, h1, ao); ao = fmaf(Wo2, h2, ao); ao = fmaf(Wo3, h3, ao);
        const float Ei = fexp2(ai);
        const float Ef = fexp2(af);
        const float Eg = fexp2(ag);
        const float Eo = fexp2(ao);
        const float pi_ = 1.0f + Ei, pf_ = 1.0f + Ef, pg_ = 1.0f + Eg, po_ = 1.0f + Eo;
        const float t1  = pi_ * pg_;
        const float num = fmaf(c, t1, (1.0f - Eg) * pf_);
        const float den = t1 * pf_;
        c = num * frcp(den);
        const float Ec  = fexp2(sg * c);
        const float pc_ = 1.0f + Ec;
        h = (1.0f - Ec) * frcp(po_ * pc_);
    };

    const float4* xv4 = (const float4*)(x + (size_t)b * (size_t)T);
    const int nch = T >> 2;
    float4 cur = xv4[0];
    for (int ch = 0; ch < nch; ++ch) {
        const int ni = ((ch + 1) < nch) ? (ch + 1) : ch;
        float4 nxt = xv4[ni];           // prefetch next chunk before compute
        STEP(cur.x); STEP(cur.y); STEP(cur.z); STEP(cur.w);
        cur = nxt;
    }
    // tail (T % 4 != 0) — not hit for T=1024, kept for safety
    for (int t = nch << 2; t < T; ++t) STEP(x[(size_t)b * T + t]);

    // logits[b] = sum_j h_j * fc_w[j] + fc_b  (quad butterfly reduce)
    float v = h * fc_w[j];
    v += hxor<1>(v);
    v += hxor<2>(v);
    if (j == 0) out[b] = v + fc_b[0];
}

extern "C" void kernel_launch(void* const* d_in, const int* in_sizes, int n_in,
                              void* d_out, int out_size, void* d_ws, size_t ws_size,
                              hipStream_t stream) {
    const float* x    = (const float*)d_in[0];
    const float* W_ih = (const float*)d_in[1];
    const float* W_hh = (const float*)d_in[2];
    const float* b_ih = (const float*)d_in[3];
    const float* b_hh = (const float*)d_in[4];
    const float* fc_w = (const float*)d_in[5];
    const float* fc_b = (const float*)d_in[6];
    float* out = (float*)d_out;

    const int B = out_size;             // [B,1] logits
    const int T = in_sizes[0] / B;      // I = 1

    const int threads = 256;
    const int total = B * 4;            // 4 lanes per batch element
    const int grid = (total + threads - 1) / threads;
    lstm_h4_kernel<<<grid, threads, 0, stream>>>(x, W_ih, W_hh, b_ih, b_hh,
                                                 fc_w, fc_b, out, B, T);
}

// Round 2
// 158.273 us; speedup vs baseline: 1.2971x; 1.2971x over previous
//
#include <hip/hip_runtime.h>
#include <hip/hip_bf16.h>

#define LOG2E 1.4426950408889634f

typedef float f32x2 __attribute__((ext_vector_type(2)));

// ---- native transcendentals (never fall back to lib exp2f / IEEE divide) ----
__device__ __forceinline__ float fexp2(float x) {
#if __has_builtin(__builtin_amdgcn_exp2f)
    return __builtin_amdgcn_exp2f(x);
#else
    float r; asm("v_exp_f32 %0, %1" : "=v"(r) : "v"(x)); return r;
#endif
}
__device__ __forceinline__ float frcp(float x) {
#if __has_builtin(__builtin_amdgcn_rcpf)
    return __builtin_amdgcn_rcpf(x);
#else
    float r; asm("v_rcp_f32 %0, %1" : "=v"(r) : "v"(x)); return r;
#endif
}
__device__ __forceinline__ f32x2 vexp2(f32x2 x) { f32x2 r; r.x = fexp2(x.x); r.y = fexp2(x.y); return r; }
__device__ __forceinline__ f32x2 vrcp (f32x2 x) { f32x2 r; r.x = frcp(x.x); r.y = frcp(x.y); return r; }

// packed fma: lowers to v_pk_fma_f32 on gfx90a+ (<2 x float> llvm.fma)
__device__ __forceinline__ f32x2 pk_fma(f32x2 a, f32x2 b, f32x2 c) {
#if __has_builtin(__builtin_elementwise_fma)
    return __builtin_elementwise_fma(a, b, c);
#else
    f32x2 r; r.x = fmaf(a.x, b.x, c.x); r.y = fmaf(a.y, b.y, c.y); return r;
#endif
}
__device__ __forceinline__ f32x2 sp(float v) { return (f32x2){v, v}; }

// Quad-lane XOR shuffle via DPP quad_perm (full-rate VALU, no LDS pipe).
template<int MASK>
__device__ __forceinline__ float hxor(float v) {
#if __has_builtin(__builtin_amdgcn_update_dpp)
    constexpr int ctrl = (0 ^ MASK) | ((1 ^ MASK) << 2) | ((2 ^ MASK) << 4) | ((3 ^ MASK) << 6);
    return __int_as_float(__builtin_amdgcn_update_dpp(
        0, __float_as_int(v), ctrl, 0xf, 0xf, true));
#else
    return __shfl_xor(v, MASK, 64);
#endif
}
template<int MASK>
__device__ __forceinline__ f32x2 hxor2(f32x2 v) {
    f32x2 r; r.x = hxor<MASK>(v.x); r.y = hxor<MASK>(v.y); return r;
}

// One lane = hidden unit j of TWO batch elements (b, b + B/2), packed in f32x2.
// 4 lanes (a quad) per batch-pair. Gate order (PyTorch): i,f,g,o.
// exp2 scale factors pre-folded into weights/biases.
__global__ __launch_bounds__(256, 1) void lstm_h4x2_kernel(
    const float* __restrict__ x,
    const float* __restrict__ W_ih,   // [16]
    const float* __restrict__ W_hh,   // [16][4]
    const float* __restrict__ b_ih,   // [16]
    const float* __restrict__ b_hh,   // [16]
    const float* __restrict__ fc_w,   // [4]
    const float* __restrict__ fc_b,   // [1]
    float* __restrict__ out,          // [B]
    int B, int T)
{
    const int tid  = blockIdx.x * blockDim.x + threadIdx.x;
    const int half = B >> 1;
    const int p = tid >> 2;          // batch-pair index
    const int j = tid & 3;           // hidden unit owned by this lane
    if (p >= half) return;
    const int b0 = p, b1 = p + half;

    const float si = -LOG2E;          // sigmoid: E = exp2(si*z) = e^-z
    const float sg = -2.0f * LOG2E;   // tanh:    E = exp2(sg*z) = e^-2z

    const int ri = j, rf = 4 + j, rg = 8 + j, ro = 12 + j;

    // x-path coefficients (I=1): arg_G = A_G * x_t + C_G + sum W h
    const float Ai = si * W_ih[ri], Ci = si * (b_ih[ri] + b_hh[ri]);
    const float Af = si * W_ih[rf], Cf = si * (b_ih[rf] + b_hh[rf]);
    const float Ag = sg * W_ih[rg], Cg = sg * (b_ih[rg] + b_hh[rg]);
    const float Ao = si * W_ih[ro], Co = si * (b_ih[ro] + b_hh[ro]);

    // Recurrent weights, permuted so index m pairs with h_{j^m}
    const float Wi0 = si * W_hh[ri*4 + (j^0)], Wi1 = si * W_hh[ri*4 + (j^1)];
    const float Wi2 = si * W_hh[ri*4 + (j^2)], Wi3 = si * W_hh[ri*4 + (j^3)];
    const float Wf0 = si * W_hh[rf*4 + (j^0)], Wf1 = si * W_hh[rf*4 + (j^1)];
    const float Wf2 = si * W_hh[rf*4 + (j^2)], Wf3 = si * W_hh[rf*4 + (j^3)];
    const float Wg0 = sg * W_hh[rg*4 + (j^0)], Wg1 = sg * W_hh[rg*4 + (j^1)];
    const float Wg2 = sg * W_hh[rg*4 + (j^2)], Wg3 = sg * W_hh[rg*4 + (j^3)];
    const float Wo0 = si * W_hh[ro*4 + (j^0)], Wo1 = si * W_hh[ro*4 + (j^1)];
    const float Wo2 = si * W_hh[ro*4 + (j^2)], Wo3 = si * W_hh[ro*4 + (j^3)];

    f32x2 h = sp(0.0f), c = sp(0.0f);

    // With E* = e^{-z} (sigmoid) / e^{-2z} (tanh), p* = 1+E*:
    //   c' = [c*pi*pg + (1-Eg)*pf] / (pf*pi*pg)          (1 rcp)
    //   h  = (1-Ec) * rcp(po*(1+Ec)),  Ec = e^{-2 c'}    (1 rcp)
    // (1-E)*q folded as fma(-E, q, q).
    auto STEP = [&](f32x2 xv) {
        const f32x2 h1 = hxor2<1>(h);
        const f32x2 h2 = hxor2<2>(h);
        const f32x2 h3 = hxor2<3>(h);
        f32x2 ai = pk_fma(sp(Ai), xv, sp(Ci));
        f32x2 af = pk_fma(sp(Af), xv, sp(Cf));
        f32x2 ag = pk_fma(sp(Ag), xv, sp(Cg));
        f32x2 ao = pk_fma(sp(Ao), xv, sp(Co));
        ai = pk_fma(sp(Wi0), h, ai); ai = pk_fma(sp(Wi1), h1, ai);
        ai = pk_fma(sp(Wi2), h2, ai); ai = pk_fma(sp(Wi3), h3, ai);
        af = pk_fma(sp(Wf0), h, af); af = pk_fma(sp(Wf1), h1, af);
        af = pk_fma(sp(Wf2), h2, af); af = pk_fma(sp(Wf3), h3, af);
        ag = pk_fma(sp(Wg0), h, ag); ag = pk_fma(sp(Wg1), h1, ag);
        ag = pk_fma(sp(Wg2), h2, ag); ag = pk_fma(sp(Wg3), h3, ag);
        ao = pk_fma(sp(Wo0), h, ao); ao = pk_fma(sp(Wo1), h1, ao);
        ao = pk_fma(sp(Wo2), h2, ao); ao = pk_fma(sp(Wo3), h3, ao);
        const f32x2 Ei = vexp2(ai);
        const f32x2 Ef = vexp2(af);
        const f32x2 Eg = vexp2(ag);
        const f32x2 Eo = vexp2(ao);
        const f32x2 pi_ = sp(1.0f) + Ei, pf_ = sp(1.0f) + Ef;
        const f32x2 pg_ = sp(1.0f) + Eg, po_ = sp(1.0f) + Eo;
        const f32x2 t1  = pi_ * pg_;
        const f32x2 u   = pk_fma(-Eg, pf_, pf_);      // (1-Eg)*pf
        const f32x2 num = pk_fma(c, t1, u);
        const f32x2 den = t1 * pf_;
        c = num * vrcp(den);
        const f32x2 Ec  = vexp2(sp(sg) * c);
        const f32x2 pd  = po_ * (sp(1.0f) + Ec);
        const f32x2 r   = vrcp(pd);
        h = pk_fma(-Ec, r, r);                        // (1-Ec)*rcp(po*pc)
    };

    const float4* p0 = (const float4*)(x + (size_t)b0 * (size_t)T);
    const float4* p1 = (const float4*)(x + (size_t)b1 * (size_t)T);
    const int nit = T >> 3;           // 8 steps per iteration
    float4 a0 = p0[0], a1 = p0[1];
    float4 c0 = p1[0], c1 = p1[1];
    for (int it = 0; it < nit; ++it) {
        const int ni = ((it + 1) < nit) ? (it + 1) : it;
        float4 na0 = p0[2*ni], na1 = p0[2*ni + 1];    // prefetch 8 steps ahead
        float4 nc0 = p1[2*ni], nc1 = p1[2*ni + 1];
        STEP((f32x2){a0.x, c0.x}); STEP((f32x2){a0.y, c0.y});
        STEP((f32x2){a0.z, c0.z}); STEP((f32x2){a0.w, c0.w});
        STEP((f32x2){a1.x, c1.x}); STEP((f32x2){a1.y, c1.y});
        STEP((f32x2){a1.z, c1.z}); STEP((f32x2){a1.w, c1.w});
        a0 = na0; a1 = na1; c0 = nc0; c1 = nc1;
    }
    // tail (T % 8 != 0) — not hit for T=1024, kept for safety
    for (int t = nit << 3; t < T; ++t)
        STEP((f32x2){x[(size_t)b0 * T + t], x[(size_t)b1 * T + t]});

    // logits = sum_j h_j * fc_w[j] + fc_b  (quad butterfly reduce, both chains)
    f32x2 v = h * sp(fc_w[j]);
    v = v + hxor2<1>(v);
    v = v + hxor2<2>(v);
    if (j == 0) {
        out[b0] = v.x + fc_b[0];
        out[b1] = v.y + fc_b[0];
    }
}

extern "C" void kernel_launch(void* const* d_in, const int* in_sizes, int n_in,
                              void* d_out, int out_size, void* d_ws, size_t ws_size,
                              hipStream_t stream) {
    const float* x    = (const float*)d_in[0];
    const float* W_ih = (const float*)d_in[1];
    const float* W_hh = (const float*)d_in[2];
    const float* b_ih = (const float*)d_in[3];
    const float* b_hh = (const float*)d_in[4];
    const float* fc_w = (const float*)d_in[5];
    const float* fc_b = (const float*)d_in[6];
    float* out = (float*)d_out;

    const int B = out_size;             // [B,1] logits
    const int T = in_sizes[0] / B;      // I = 1

    const int threads = 256;
    const int total = (B >> 1) * 4;     // 4 lanes per batch-PAIR
    const int grid = (total + threads - 1) / threads;
    lstm_h4x2_kernel<<<grid, threads, 0, stream>>>(x, W_ih, W_hh, b_ih, b_hh,
                                                   fc_w, fc_b, out, B, T);
}